// Round 12
// baseline (183.911 us; speedup 1.0000x reference)
//
#include <hip/hip_runtime.h>
#include <stdint.h>

typedef __attribute__((ext_vector_type(4)))  int   intx4;
typedef __attribute__((ext_vector_type(8)))  int   intx8;
typedef __attribute__((ext_vector_type(16))) float floatx16;

#define GLL16(gp, lp)                                                               \
    __builtin_amdgcn_global_load_lds((const __attribute__((address_space(1))) unsigned int*)(gp), \
                                     (__attribute__((address_space(3))) unsigned int*)(lp), 16, 0, 0)
#define GLL4(gp, lp)                                                                \
    __builtin_amdgcn_global_load_lds((const __attribute__((address_space(1))) unsigned int*)(gp), \
                                     (__attribute__((address_space(3))) unsigned int*)(lp), 4, 0, 0)

// ---------------------------------------------------------------------------
// RTE onto the e2m1 grid {0,.5,1,1.5,2,3,4,6} -> code 0..7 (ties-to-even,
// matches ref searchsorted+tie-fix). Sign -> bit 3. (proven)
// ---------------------------------------------------------------------------
__device__ __forceinline__ uint32_t enc1(float xv, float inv) {
    float a = fminf(fabsf(xv) * inv, 6.0f);
    int e;
    if (a < 2.0f)      e = (int)rintf(a + a);          // 0,.5,1,1.5,2 -> 0..4
    else if (a < 4.0f) e = (int)rintf(a) + 2;          // 2,3,4        -> 4..6
    else               e = (int)rintf(a * 0.5f) + 4;   // 4,6          -> 6,7
    return (uint32_t)e | ((__float_as_uint(xv) >> 28) & 8u);
}

// ---------------------------------------------------------------------------
// Kernel 1 (merged prep, single launch — R11 structure, proven):
//   blocks [0, nq)        : quantize x -> xq + scales direct to interleaved
//                           xs_il[c][m][j] (j = kb-8c; scatter proven cheap)
//   blocks [nq, nq+nwb)   : densify weight nibbles -> wrep
//   blocks [nq+nwb, +ntb) : transpose wsc [n][kb] -> ws_il[c][n][j]
// ---------------------------------------------------------------------------
__global__ __launch_bounds__(256) void prep_kernel(const float* __restrict__ x,
                                                   uint32_t* __restrict__ xq,
                                                   uint8_t* __restrict__ xs_il,
                                                   int nq, int M,
                                                   const int* __restrict__ wp,
                                                   uint32_t* __restrict__ wrep,
                                                   int nwb,
                                                   const int* __restrict__ wsc,
                                                   uint8_t* __restrict__ ws_il,
                                                   int N, int Ck) {
    const int bid = blockIdx.x;
    const int t = threadIdx.x;
    if (bid < nq) {                               // ---- quantize x ----
        const int gl = bid * 256 + t;             // lane over M*K/4
        const float4 v = ((const float4*)x)[gl];
        float m = fmaxf(fmaxf(fabsf(v.x), fabsf(v.y)), fmaxf(fabsf(v.z), fabsf(v.w)));
        m = fmaxf(m, __shfl_xor(m, 1));
        m = fmaxf(m, __shfl_xor(m, 2));
        m = fmaxf(m, __shfl_xor(m, 4));           // 8-lane group = 1 MX block
        const unsigned ef = __float_as_uint(m) >> 23;
        const unsigned code = (ef < 3u) ? 1u : (ef - 2u);       // FLOOR scale
        const float inv = __uint_as_float((254u - code) << 23); // 2^(127-code)
        const uint32_t p = enc1(v.x, inv)        | (enc1(v.y, inv) << 4)
                         | (enc1(v.z, inv) << 8) | (enc1(v.w, inv) << 12);
        ((uint16_t*)xq)[gl] = (uint16_t)p;        // coalesced 2 B/lane
        if ((gl & 7) == 0) {                      // one scale byte / MX block
            const int blk = gl >> 3;              // m*128 + kb
            const int mm = blk >> 7, kb = blk & 127;
            xs_il[(size_t)(kb >> 3) * ((size_t)M * 8) + (size_t)mm * 8 + (kb & 7)]
                = (uint8_t)code;
        }
        return;
    }
    if (bid < nq + nwb) {                         // ---- wrep densify ----
        const int i = (bid - nq) * 256 + t;
        const int4 p = ((const int4*)wp)[i];
        wrep[i] = (uint32_t)(p.x & 0xFF) | ((uint32_t)(p.y & 0xFF) << 8)
                | ((uint32_t)(p.z & 0xFF) << 16) | ((uint32_t)(p.w & 0xFF) << 24);
        return;
    }
    // ---- W-scale transpose/interleave: tile 128 rows x 32 kb ----
    __shared__ uint8_t raw[128 * 32];
    const int tidx = bid - nq - nwb;              // 0..127
    const int n0 = (tidx & 31) * 128;             // row base (N/128 = 32)
    const int c0 = (tidx >> 5) * 32;              // kb base  (Ck/32 = 4)
    {
        const int r = t >> 1, hf = t & 1;
        const size_t base = (size_t)(n0 + r) * Ck + c0 + hf * 16;
        uint32_t b[4];
#pragma unroll
        for (int j = 0; j < 4; ++j) {
            const int4 p = *(const int4*)(wsc + base + 4 * j);
            b[j] = (uint32_t)(p.x & 0xFF) | ((uint32_t)(p.y & 0xFF) << 8)
                 | ((uint32_t)(p.z & 0xFF) << 16) | ((uint32_t)(p.w & 0xFF) << 24);
        }
        *(uint4*)(raw + r * 32 + hf * 16) = make_uint4(b[0], b[1], b[2], b[3]);
    }
    __syncthreads();
    const int ml = t & 127;
#pragma unroll
    for (int pp = 0; pp < 2; ++pp) {
        const int ckl = (t >> 7) * 2 + pp;        // local chunk 0..3
        const int base = ml * 32 + ckl * 8;
        const uint32_t lo = (uint32_t)raw[base + 0] | ((uint32_t)raw[base + 1] << 8)
                          | ((uint32_t)raw[base + 2] << 16) | ((uint32_t)raw[base + 3] << 24);
        const uint32_t hi = (uint32_t)raw[base + 4] | ((uint32_t)raw[base + 5] << 8)
                          | ((uint32_t)raw[base + 6] << 16) | ((uint32_t)raw[base + 7] << 24);
        *(uint2*)(ws_il + (size_t)(c0 / 8 + ckl) * ((size_t)N * 8)
                        + (size_t)(n0 + ml) * 8) = make_uint2(lo, hi);
    }
}

// ---------------------------------------------------------------------------
// Kernel 2: MXFP4 GEMM, 128x128 tile, BK=256, 4 waves x (2x2) — R6/R11
// structure (best: 55.7 us). Single buffer, 2x __syncthreads, 4 blocks/CU,
// piece swizzle p = w ^ (r&7).
//
// Round-12 single variable: scale LDS layout [row][j0..7] (8 B/row). Per
// chunk each wave reads 4x ds_read_b64 (one per operand row) instead of
// 16x ds_read_u8 — saves ~1.2K LDS-port cycles/CU/chunk (the port is ~80%
// busy, the critical pipe). Byte extracted by VALU shift: word = s>>1
// (compile-time), shift = 8h (s even) / 16+8h (s odd). b64 reads: 2-way
// row alias + h-broadcast = conflict-free. Staging: 2 coalesced GLL4s per
// thread from the interleaved arrays (identical instruction count).
// ---------------------------------------------------------------------------
__global__ __launch_bounds__(256) void gemm_mx_kernel(const uint8_t* __restrict__ Apk,
                                                      const uint8_t* __restrict__ Bpk,
                                                      const uint8_t* __restrict__ Asil,
                                                      const uint8_t* __restrict__ Bsil,
                                                      float* __restrict__ C,
                                                      int M, int N, int K) {
    __shared__ __align__(16) uint8_t sA[16384];   // 128 rows x 128 B
    __shared__ __align__(16) uint8_t sB[16384];
    __shared__ __align__(16) uint8_t sS[2048];    // A: [row][j0..7] | B: [row][j0..7]

    const int tid = threadIdx.x;
    const int bm0 = blockIdx.y << 7;
    const int bn0 = blockIdx.x << 7;
    const int wave = tid >> 6;
    const int lane = tid & 63;
    const int wm = (wave >> 1) << 6;
    const int wn = (wave & 1) << 6;
    const int row = lane & 31;
    const int h = lane >> 5;
    const int Kb = K >> 1;                        // packed bytes per row (2048)

    // data staging: 1024 slots/tile (128 rows x 8 pieces), 4 slots/thread.
    // slot s: row r = s>>3, within-row slot w = s&7, piece p = w ^ (r&7)
    const uint8_t* Ag[4];
    const uint8_t* Bg[4];
#pragma unroll
    for (int i = 0; i < 4; ++i) {
        const int s = tid + 256 * i;
        const int r = s >> 3;
        const int p = (s & 7) ^ (r & 7);
        Ag[i] = Apk + (size_t)(bm0 + r) * Kb + p * 16;
        Bg[i] = Bpk + (size_t)(bn0 + r) * Kb + p * 16;
    }

    // scale staging: waves 0-1 -> A rows, waves 2-3 -> B rows. Thread t
    // stages words t and t+128 of its 256-word region: word w = row w>>1,
    // half w&1 -> LDS [row][j] layout; both GLL4s coalesced (256 B/wave).
    const int st = tid & 127;
    const size_t sRb = (size_t)((tid < 128) ? M : N) * 8;
    const uint8_t* Sg1 = ((tid < 128) ? Asil + (size_t)(bm0 + (st >> 1)) * 8
                                      : Bsil + (size_t)(bn0 + (st >> 1)) * 8)
                         + (st & 1) * 4;
    const uint8_t* Sg2 = Sg1 + 512;               // +64 rows * 8 B
    const int soff = ((tid < 128) ? 0 : 1024) + st * 4;

    floatx16 acc[2][2];
#pragma unroll
    for (int a = 0; a < 2; ++a)
#pragma unroll
        for (int b = 0; b < 2; ++b)
#pragma unroll
            for (int r = 0; r < 16; ++r) acc[a][b][r] = 0.f;

    const int nchunk = K >> 8;                    // 16
    const int ar0 = wm + row, ar1 = wm + 32 + row;
    const int br0 = wn + row, br1 = wn + 32 + row;
    const int shE = h * 8;                        // shift for even s
    const int shO = 16 + h * 8;                   // shift for odd s

    for (int c = 0; c < nchunk; ++c) {
        __syncthreads();
        const size_t koff = (size_t)c << 7;       // 128 B per chunk
#pragma unroll
        for (int i = 0; i < 4; ++i) GLL16(Ag[i] + koff, sA + (tid + 256 * i) * 16);
#pragma unroll
        for (int i = 0; i < 4; ++i) GLL16(Bg[i] + koff, sB + (tid + 256 * i) * 16);
        GLL4(Sg1 + (size_t)c * sRb, sS + soff);
        GLL4(Sg2 + (size_t)c * sRb, sS + soff + 512);
        __syncthreads();

        // all 8 per-kp scales for this wave's 4 operand rows: 4x b64
        const uint2 sa0 = *(const uint2*)(sS + ar0 * 8);
        const uint2 sa1 = *(const uint2*)(sS + ar1 * 8);
        const uint2 sb0 = *(const uint2*)(sS + 1024 + br0 * 8);
        const uint2 sb1 = *(const uint2*)(sS + 1024 + br1 * 8);

#pragma unroll
        for (int s = 0; s < 4; ++s) {
            const int kp = 2 * s + h;             // 16B piece / MX-block index 0..7
            intx4 a4[2], b4[2];
            a4[0] = *(const intx4*)(sA + ar0 * 128 + ((kp ^ (ar0 & 7)) << 4));
            a4[1] = *(const intx4*)(sA + ar1 * 128 + ((kp ^ (ar1 & 7)) << 4));
            b4[0] = *(const intx4*)(sB + br0 * 128 + ((kp ^ (br0 & 7)) << 4));
            b4[1] = *(const intx4*)(sB + br1 * 128 + ((kp ^ (br1 & 7)) << 4));
            const uint32_t wa0 = (s & 2) ? sa0.y : sa0.x;   // word = s>>1
            const uint32_t wa1 = (s & 2) ? sa1.y : sa1.x;
            const uint32_t wb0 = (s & 2) ? sb0.y : sb0.x;
            const uint32_t wb1 = (s & 2) ? sb1.y : sb1.x;
            const int sh = (s & 1) ? shO : shE;
            const int sa[2] = { (int)((wa0 >> sh) & 0xFF), (int)((wa1 >> sh) & 0xFF) };
            const int sb[2] = { (int)((wb0 >> sh) & 0xFF), (int)((wb1 >> sh) & 0xFF) };
#pragma unroll
            for (int mt = 0; mt < 2; ++mt)
#pragma unroll
                for (int nt = 0; nt < 2; ++nt) {
                    intx8 a8 = {a4[mt][0], a4[mt][1], a4[mt][2], a4[mt][3], 0, 0, 0, 0};
                    intx8 b8 = {b4[nt][0], b4[nt][1], b4[nt][2], b4[nt][3], 0, 0, 0, 0};
                    acc[mt][nt] = __builtin_amdgcn_mfma_scale_f32_32x32x64_f8f6f4(
                        a8, b8, acc[mt][nt], 4, 4, 0, sa[mt], 0, sb[nt]);
                }
        }
    }

    // C/D layout (32x32): col = lane&31, row = (reg&3) + 8*(reg>>2) + 4*(lane>>5)
#pragma unroll
    for (int mt = 0; mt < 2; ++mt)
#pragma unroll
        for (int nt = 0; nt < 2; ++nt) {
            const int col = bn0 + wn + nt * 32 + row;
#pragma unroll
            for (int g = 0; g < 4; ++g) {
                const int rw = bm0 + wm + mt * 32 + 8 * g + 4 * h;
#pragma unroll
                for (int q = 0; q < 4; ++q)
                    C[(size_t)(rw + q) * N + col] = acc[mt][nt][4 * g + q];
            }
        }
}

// ---------------------------------------------------------------------------
extern "C" void kernel_launch(void* const* d_in, const int* in_sizes, int n_in,
                              void* d_out, int out_size, void* d_ws, size_t ws_size,
                              hipStream_t stream) {
    const float* x = (const float*)d_in[0];
    const int* wp = (const int*)d_in[1];
    const int* wsc = (const int*)d_in[2];
    float* out = (float*)d_out;

    const int K = 4096;
    const int M = in_sizes[0] / K;            // 4096
    const int N = (in_sizes[1] * 2) / K;      // 4096
    const int kbpr = K / 32;                  // 128
    const int npack = N * K / 2;              // weight packed bytes

    uint32_t* xq    = (uint32_t*)d_ws;                                 // 8 MiB
    uint8_t*  xs_il = (uint8_t*)d_ws + (size_t)M * K / 2;              // 512 KiB [c][m][j]
    uint32_t* wrep  = (uint32_t*)(xs_il + (size_t)M * kbpr);           // 8 MiB
    uint8_t*  ws_il = (uint8_t*)(wrep + (size_t)npack / 4);            // 512 KiB [c][n][j]

    const int nq  = (M * K / 4) / 256;        // quant blocks (16384)
    const int nwb = npack / 4 / 256;          // wrep blocks (8192)
    const int ntb = (N / 128) * (kbpr / 32);  // W-scale transpose tiles (128)

    prep_kernel<<<nq + nwb + ntb, 256, 0, stream>>>(x, xq, xs_il, nq, M,
                                                    wp, wrep, nwb,
                                                    wsc, ws_il, N, kbpr);

    dim3 grid(N / 128, M / 128);
    gemm_mx_kernel<<<grid, 256, 0, stream>>>((const uint8_t*)xq, (const uint8_t*)wrep,
                                             xs_il, ws_il, out, M, N, K);
}